// Round 7
// baseline (96.858 us; speedup 1.0000x reference)
//
#include <hip/hip_runtime.h>

#define NB 32
#define TT 512
#define UU 100
#define UM 101   // U+1
#define VV 4096
#define NEG (-1e30f)
#define WIN 64
#define NWIN 11          // producer windows: d in [1, 704]
#define DST 720          // stream d-stride per n
#define PW 16            // consumer ring depth
#define L2E 1.4426950408889634f
#define LN2 0.6931471805599453f

__device__ __forceinline__ float vexp2(float x){ float r; asm("v_exp_f32 %0, %1" : "=v"(r) : "v"(x)); return r; }
__device__ __forceinline__ float vlog2(float x){ float r; asm("v_log_f32 %0, %1" : "=v"(r) : "v"(x)); return r; }

// logaddexp in log2 domain
__device__ __forceinline__ float lae2(float a, float b) {
    float m  = fmaxf(a, b);
    float nd = fminf(a, b) - m;          // = -|a-b|
    return m + vlog2(1.0f + vexp2(nd));
}

__global__ void clear_k(int* __restrict__ flags) {
    flags[threadIdx.x] = 0;              // 512 = NB*16
}

// blocks 0..31: DP consumer for n = bid (wave 0 of the block).
// blocks 32..383: producer for (n, w) = divmod(bid-32, NWIN); gathers one
//   64-diagonal window of the emit stream st[n][d][u] (u = 0..127, d = w*64+1..w*64+64),
//   then flags it. Full-chip gather concurrency, overlapped with the DP.
__global__ __launch_bounds__(256, 1) void fused_k(
        const float* __restrict__ enc, const float* __restrict__ dec,
        const int* __restrict__ tgt, const int* __restrict__ ilen,
        const int* __restrict__ tlen,
        float* __restrict__ st, int* __restrict__ flags, float* __restrict__ out) {
    int bid = blockIdx.x;
    int tid = threadIdx.x;

    if (bid >= NB) {
        // ---------------- producer ----------------
        int pb = bid - NB;
        int n = pb / NWIN, w = pb % NWIN;
        __shared__ int   tgtL[UU];
        __shared__ float dvxL[UU];
        if (tid < UU) {
            int y = tgt[n * UU + tid];
            tgtL[tid] = y;
            dvxL[tid] = dec[((size_t)n * UM + tid) * VV + y] * L2E;
        }
        int tin = ilen[n], tg = tlen[n];
        __syncthreads();
        const float* encn = enc + (size_t)n * TT * VV;
        float* F = st + ((size_t)n * DST + (size_t)(w * WIN + 1)) * 128;
#pragma unroll
        for (int it = 0; it < 32; ++it) {
            int idx = tid + it * 256;           // 0..8191, exact
            int dm = idx >> 7, u = idx & 127;
            int d = w * WIN + 1 + dm;
            int t = d - u;
            float val = NEG;
            if (u >= 1 && u <= tg && t >= 0 && t < tin)
                val = fmaf(encn[(size_t)t * VV + tgtL[u - 1]], L2E, dvxL[u - 1]);
            F[idx] = val;
        }
        __syncthreads();                         // drains vmcnt (stores at L2)
        if (tid == 0) {
            __threadfence();                     // agent-scope: L2 writeback
            atomicExch(&flags[n * 16 + w], 1);   // device-scope, coherent
        }
        return;
    }

    // ---------------- consumer (one wave per n) ----------------
    int n = bid;
    __shared__ float blkL[864];   // blkL[128+t] = enc[n][t][0]*L2E, NEG pads
    const float* encn = enc + (size_t)n * TT * VV;
    for (int i = tid; i < 864; i += 256)
        blkL[i] = (i >= 128 && i < 128 + TT) ? encn[(size_t)(i - 128) * VV] * L2E : NEG;
    __syncthreads();
    if (tid >= 64) return;        // waves 1..3 done
    int lane = tid;

    int tin = ilen[n], tg = tlen[n];
    int dend = tin - 1 + tg;
    int WC = (dend + WIN - 1) / WIN;             // 8..10 windows to consume
    const float* decn = dec + (size_t)n * UM * VV;
    float bd0 = decn[(size_t)min(2 * lane, UM - 1) * VV] * L2E;      // junk-safe clamp
    float bd1 = decn[(size_t)min(2 * lane + 1, UM - 1) * VV] * L2E;
    const float* sp = st + (size_t)n * DST * 128 + 2 * lane;
    int ib0 = 127 - 2 * lane;     // blkL idx of slot0's blk[t-1] is ib0 + d
    bool cap0 = (2 * lane == tg), cap1 = (2 * lane + 1 == tg);
    bool fx16 = (lane == 16), fx32 = (lane == 32), fx48 = (lane == 48);
    float a0 = (lane == 0) ? 0.0f : NEG;         // alpha[0][0] = 0 at d=0
    float a1 = NEG;
    float res = NEG;
    int* flg = flags + n * 16;

    float Ae0[PW], Ae1[PW], Ab0[PW], Ab1[PW];
    float Be0[PW], Be1[PW], Bb0[PW], Bb1[PW];

    auto WAIT = [&](int w) {
        if (lane == 0) { while (atomicAdd(&flg[w], 0) == 0) {} }
        __threadfence();                         // acquire side
    };

    auto REFILL = [&](float (&Re0)[PW], float (&Re1)[PW],
                      float (&Rb0)[PW], float (&Rb1)[PW], int d0) {
#pragma unroll
        for (int k = 0; k < PW; ++k) {
            int d = d0 + k;
            float2 ev = *(const float2*)(sp + (size_t)d * 128);
            Re0[k] = ev.x; Re1[k] = ev.y;
            Rb0[k] = blkL[ib0 + d] + bd0;
            Rb1[k] = blkL[ib0 + d - 1] + bd1;
        }
        __builtin_amdgcn_sched_barrier(0);
    };

    auto STEPS = [&](float (&Re0)[PW], float (&Re1)[PW],
                     float (&Rb0)[PW], float (&Rb1)[PW], int d0) {
#pragma unroll
        for (int k = 0; k < PW; ++k) {
            int dd = d0 + k;
            // left neighbor of u=2L is lane L-1's a1: DPP row_shr:1 + seam fixups
            int sh = __builtin_amdgcn_update_dpp(__float_as_int(NEG), __float_as_int(a1),
                                                 0x111, 0xF, 0xF, false);   // row_shr:1
            float s15 = __int_as_float(__builtin_amdgcn_readlane(__float_as_int(a1), 15));
            float s31 = __int_as_float(__builtin_amdgcn_readlane(__float_as_int(a1), 31));
            float s47 = __int_as_float(__builtin_amdgcn_readlane(__float_as_int(a1), 47));
            float l0 = __int_as_float(sh);
            l0 = fx16 ? s15 : l0;
            l0 = fx32 ? s31 : l0;
            l0 = fx48 ? s47 : l0;
            float bt0 = a0 + Rb0[k], et0 = l0 + Re0[k];
            float bt1 = a1 + Rb1[k], et1 = a0 + Re1[k];   // old a0: same-lane left neighbor
            a0 = lae2(bt0, et0);
            a1 = lae2(bt1, et1);
            if (dd == dend) { if (cap0) res = a0; if (cap1) res = a1; }
        }
        __builtin_amdgcn_sched_barrier(0);
    };

    WAIT(0);
    REFILL(Ae0, Ae1, Ab0, Ab1, 1);               // window 0, d 1..16
    for (int w = 0; w < WC; ++w) {
        int b = w * WIN;                         // window covers d = b+1 .. b+64
        REFILL(Be0, Be1, Bb0, Bb1, b + 17); STEPS(Ae0, Ae1, Ab0, Ab1, b + 1);
        REFILL(Ae0, Ae1, Ab0, Ab1, b + 33); STEPS(Be0, Be1, Bb0, Bb1, b + 17);
        REFILL(Be0, Be1, Bb0, Bb1, b + 49); STEPS(Ae0, Ae1, Ab0, Ab1, b + 33);
        if (w + 1 < WC) WAIT(w + 1);
        REFILL(Ae0, Ae1, Ab0, Ab1, b + 65); STEPS(Be0, Be1, Bb0, Bb1, b + 49);
        // note: final REFILL of the last iteration reads window WC unflagged;
        // those values are never consumed (loop ends) — junk-safe.
    }

    if (cap0 | cap1) {
        float fin  = blkL[128 + tin - 1];
        float bdtg = decn[(size_t)tg * VV] * L2E;
        out[n] = (res + fin + bdtg) * LN2;
    }
}

extern "C" void kernel_launch(void* const* d_in, const int* in_sizes, int n_in,
                              void* d_out, int out_size, void* d_ws, size_t ws_size,
                              hipStream_t hs) {
    const float* enc  = (const float*)d_in[0];
    const float* dec  = (const float*)d_in[1];
    const int*   tgt  = (const int*)d_in[2];
    const int*   ilen = (const int*)d_in[3];
    const int*   tlen = (const int*)d_in[4];
    float* out = (float*)d_out;

    float* st    = (float*)d_ws;                          // NB*DST*128 floats = 11.8 MB
    int*   flags = (int*)(st + (size_t)NB * DST * 128);   // NB*16 ints

    hipLaunchKernelGGL(clear_k, dim3(1), dim3(NB * 16), 0, hs, flags);
    hipLaunchKernelGGL(fused_k, dim3(NB + NB * NWIN), dim3(256), 0, hs,
                       enc, dec, tgt, ilen, tlen, st, flags, out);
}

// Round 8
// 89.783 us; speedup vs baseline: 1.0788x; 1.0788x over previous
//
#include <hip/hip_runtime.h>

#define NB 32
#define TT 512
#define UU 100
#define UM 101   // U+1
#define VV 4096
#define NEG (-1e30f)
#define WIN 64
#define L2E 1.4426950408889634f
#define LN2 0.6931471805599453f

__device__ __forceinline__ float vexp2(float x){ float r; asm("v_exp_f32 %0, %1" : "=v"(r) : "v"(x)); return r; }
__device__ __forceinline__ float vlog2(float x){ float r; asm("v_log_f32 %0, %1" : "=v"(r) : "v"(x)); return r; }

// logaddexp in log2 domain
__device__ __forceinline__ float lae2(float a, float b) {
    float m  = fmaxf(a, b);
    float nd = fminf(a, b) - m;          // = -|a-b|
    return m + vlog2(1.0f + vexp2(nd));
}

// One block per batch element n. Wave 0 = DP consumer; waves 1..15 = producers.
// Producers gather emit values AND precompute blank edges for the next
// 64-diagonal window into a double-buffered LDS ring of float4{e0,b0,e1,b1}.
// Freeze semantics: for cells with t >= tin the blank edge is 0 and emit is
// NEG, so after d == dend the target column's alpha is copied forward
// unchanged — no per-step result capture needed.
__global__ __launch_bounds__(1024, 1) void fused_k(
        const float* __restrict__ enc, const float* __restrict__ dec,
        const int* __restrict__ tgt, const int* __restrict__ ilen,
        const int* __restrict__ tlen, float* __restrict__ out) {
    __shared__ float4 em[2][WIN][64];   // 128 KB: em[w][dm][L] = {e(2L),b(2L),e(2L+1),b(2L+1)}
    __shared__ float blkL[864];         // blkL[128+t] = enc[n][t][0]*L2E, NEG pads
    __shared__ float bdL[128];          // dec[n][u][0]*L2E, 0 pad
    __shared__ int   tgtL[UU];
    __shared__ float dvxL[UU];          // dec[n][j][y_j]*L2E

    int n = blockIdx.x, tid = threadIdx.x;
    int tin = ilen[n], tg = tlen[n];
    int dend = tin - 1 + tg;
    int E = (dend + WIN - 1) / WIN;
    const float* encn = enc + (size_t)n * TT * VV;
    const float* decn = dec + (size_t)n * UM * VV;

    for (int i = tid; i < 864; i += 1024)
        blkL[i] = (i >= 128 && i < 128 + TT) ? encn[(size_t)(i - 128) * VV] * L2E : NEG;
    if (tid < 128) bdL[tid] = (tid < UM) ? decn[(size_t)tid * VV] * L2E : 0.0f;
    if (tid < UU) {
        int y = tgt[n * UU + tid];
        tgtL[tid] = y;
        dvxL[tid] = decn[(size_t)tid * VV + y] * L2E;
    }
    __syncthreads();

    int wave = tid >> 6, lane = tid & 63;

    // producers: phase 1 issues ALL gather loads unconditionally (clamped
    // addresses, no branches) -> 10 independent misses in flight per lane;
    // phase 2 selects/guards and writes LDS.
    auto FILLWIN = [&](int w, int base) {
        int pid = tid - 64;              // 0..959
        float e0r[5], e1r[5];
#pragma unroll
        for (int it = 0; it < 5; ++it) {
            int idx = min(pid + it * 960, WIN * 64 - 1);
            int dm = idx >> 6, L = idx & 63;
            int d = base + 1 + dm;
            int t0 = d - 2 * L, t1 = t0 - 1;
            int tc0 = min(max(t0, 0), tin - 1), tc1 = min(max(t1, 0), tin - 1);
            int uc0 = min(max(2 * L, 1), tg),   uc1 = min(2 * L + 1, tg);
            e0r[it] = encn[(size_t)tc0 * VV + tgtL[uc0 - 1]];
            e1r[it] = encn[(size_t)tc1 * VV + tgtL[uc1 - 1]];
        }
#pragma unroll
        for (int it = 0; it < 5; ++it) {
            int idx = pid + it * 960;
            if (idx < WIN * 64) {
                int dm = idx >> 6, L = idx & 63;
                int d = base + 1 + dm;
                int u0 = 2 * L, u1 = 2 * L + 1;
                int t0 = d - u0, t1 = t0 - 1;
                int uc0 = min(max(u0, 1), tg), uc1 = min(u1, tg);
                bool ok0 = (u0 >= 1) & (u0 <= tg) & (t0 >= 0) & (t0 < tin);
                bool ok1 = (u1 <= tg) & (t1 >= 0) & (t1 < tin);
                float e0 = ok0 ? fmaf(e0r[it], L2E, dvxL[uc0 - 1]) : NEG;
                float e1 = ok1 ? fmaf(e1r[it], L2E, dvxL[uc1 - 1]) : NEG;
                float b0 = (t0 >= 1 && t0 < tin) ? blkL[128 + t0 - 1] + bdL[u0]
                                                 : (t0 >= tin ? 0.0f : NEG);
                float b1 = (t1 >= 1 && t1 < tin) ? blkL[128 + t1 - 1] + bdL[u1]
                                                 : (t1 >= tin ? 0.0f : NEG);
                em[w][dm][L] = make_float4(e0, b0, e1, b1);
            }
        }
    };

    if (wave != 0) FILLWIN(0, 0);       // prefill window 0

    // consumer state (declared for all; only wave 0 uses it)
    bool fx16 = (lane == 16), fx32 = (lane == 32), fx48 = (lane == 48);
    float a0 = (lane == 0) ? 0.0f : NEG;   // alpha[0][0] = 0 at d=0
    float a1 = NEG;
    float4 R0[8], R1[8];

    auto STEP = [&](float4 v) {
        // left neighbor of u=2L is lane L-1's a1: DPP row_shr:1 + seam fixups
        int sh = __builtin_amdgcn_update_dpp(__float_as_int(NEG), __float_as_int(a1),
                                             0x111, 0xF, 0xF, false);   // row_shr:1
        float s15 = __int_as_float(__builtin_amdgcn_readlane(__float_as_int(a1), 15));
        float s31 = __int_as_float(__builtin_amdgcn_readlane(__float_as_int(a1), 31));
        float s47 = __int_as_float(__builtin_amdgcn_readlane(__float_as_int(a1), 47));
        float l0 = __int_as_float(sh);
        l0 = fx16 ? s15 : l0;
        l0 = fx32 ? s31 : l0;
        l0 = fx48 ? s47 : l0;
        float bt0 = a0 + v.y, et0 = l0 + v.x;
        float bt1 = a1 + v.w, et1 = a0 + v.z;   // old a0: same-lane left neighbor
        a0 = lae2(bt0, et0);
        a1 = lae2(bt1, et1);
    };
    auto LD8 = [&](float4 (&R)[8], const float4* emw, int j0) {
#pragma unroll
        for (int k = 0; k < 8; ++k) R[k] = emw[(size_t)(j0 + k) * 64 + lane];
        __builtin_amdgcn_sched_barrier(0);
    };
    auto ST8 = [&](float4 (&R)[8]) {
#pragma unroll
        for (int k = 0; k < 8; ++k) STEP(R[k]);
        __builtin_amdgcn_sched_barrier(0);
    };

    __syncthreads();                    // window 0 ready

    for (int e = 0; e < E; ++e) {
        if (wave == 0) {
            const float4* emw = &em[e & 1][0][0];
            LD8(R0, emw, 0);
            LD8(R1, emw, 8);  ST8(R0);
            LD8(R0, emw, 16); ST8(R1);
            LD8(R1, emw, 24); ST8(R0);
            LD8(R0, emw, 32); ST8(R1);
            LD8(R1, emw, 40); ST8(R0);
            LD8(R0, emw, 48); ST8(R1);
            LD8(R1, emw, 56); ST8(R0);
            ST8(R1);
        } else if (e + 1 < E) {
            FILLWIN((e + 1) & 1, (e + 1) * WIN);
        }
        __syncthreads();
    }

    if (wave == 0) {
        bool cap0 = (2 * lane == tg), cap1 = (2 * lane + 1 == tg);
        if (cap0 | cap1) {
            float res = cap0 ? a0 : a1;      // frozen at d = dend by construction
            float fin = blkL[128 + tin - 1];
            float bdtg = bdL[tg];
            out[n] = (res + fin + bdtg) * LN2;
        }
    }
}

extern "C" void kernel_launch(void* const* d_in, const int* in_sizes, int n_in,
                              void* d_out, int out_size, void* d_ws, size_t ws_size,
                              hipStream_t hs) {
    const float* enc  = (const float*)d_in[0];
    const float* dec  = (const float*)d_in[1];
    const int*   tgt  = (const int*)d_in[2];
    const int*   ilen = (const int*)d_in[3];
    const int*   tlen = (const int*)d_in[4];
    float* out = (float*)d_out;

    hipLaunchKernelGGL(fused_k, dim3(NB), dim3(1024), 0, hs,
                       enc, dec, tgt, ilen, tlen, out);
}

// Round 9
// 73.290 us; speedup vs baseline: 1.3216x; 1.2250x over previous
//
#include <hip/hip_runtime.h>

#define NB 32
#define TT 512
#define UU 100
#define UM 101   // U+1
#define VV 4096
#define NEG (-1e30f)
#define PW 16            // consumer ring depth
#define WINB 32          // diagonals per build block
#define NWIN 22          // covers d = 1 .. 704 (dend_max=611, +ring overshoot 47)
#define DST 720          // stream d-stride per n
#define L2E 1.4426950408889634f
#define LN2 0.6931471805599453f

__device__ __forceinline__ float vexp2(float x){ float r; asm("v_exp_f32 %0, %1" : "=v"(r) : "v"(x)); return r; }
__device__ __forceinline__ float vlog2(float x){ float r; asm("v_log_f32 %0, %1" : "=v"(r) : "v"(x)); return r; }

// logaddexp in log2 domain
__device__ __forceinline__ float lae2(float a, float b) {
    float m  = fmaxf(a, b);
    float nd = fminf(a, b) - m;          // = -|a-b|
    return m + vlog2(1.0f + vexp2(nd));
}

// Full-chip gather: block (w, n) fills diagonals d = w*32+1 .. w*32+32 of the
// emit stream st[n][d][u] (u = 0..127). Guarded exec-masked loads (minimum
// line count) with DEFERRED uses: phase 1 issues all 16 loads into registers
// (invalid lanes keep NEG via exec mask, no data use), phase 2 selects+stores
// coalesced. 2816 waves chip-wide -> gather MLP no longer capped by 32 CUs.
__global__ __launch_bounds__(256) void build_k(
        const float* __restrict__ enc, const float* __restrict__ dec,
        const int* __restrict__ tgt, const int* __restrict__ ilen,
        const int* __restrict__ tlen, float* __restrict__ st) {
    int w = blockIdx.x, n = blockIdx.y;
    int tid = threadIdx.x;
    __shared__ int   tgtL[UU];
    __shared__ float dvxL[UU];
    if (tid < UU) {
        int y = tgt[n * UU + tid];
        tgtL[tid] = y;
        dvxL[tid] = dec[((size_t)n * UM + tid) * VV + y] * L2E;
    }
    int tin = ilen[n], tg = tlen[n];
    __syncthreads();
    const float* encn = enc + (size_t)n * TT * VV;

    float ev[16];
    // phase 1: issue all loads, no uses (MLP = 16 per lane)
#pragma unroll
    for (int it = 0; it < 16; ++it) {
        int idx = tid + it * 256;            // 0..4095
        int dm = idx >> 7, u = idx & 127;
        int d = w * WINB + 1 + dm;
        int t = d - u;
        bool ok = (u >= 1) & (u <= tg) & (t >= 0) & (t < tin);
        ev[it] = NEG;
        if (ok) ev[it] = encn[(size_t)t * VV + tgtL[u - 1]];   // exec-masked load
    }
    // phase 2: select + coalesced store (waits amortize over 16 in-flight loads)
#pragma unroll
    for (int it = 0; it < 16; ++it) {
        int idx = tid + it * 256;
        int dm = idx >> 7, u = idx & 127;
        int d = w * WINB + 1 + dm;
        int t = d - u;
        bool ok = (u >= 1) & (u <= tg) & (t >= 0) & (t < tin);
        int uc = max(u, 1);
        float e = ok ? fmaf(ev[it], L2E, dvxL[uc - 1]) : NEG;
        st[((size_t)n * DST + d) * 128 + u] = e;
    }
}

// wavefront DP (R6-proven math): lane L owns u=2L (a0) and u=2L+1 (a1).
// Emit edges from the global diagonal-major stream (512B/diagonal, L2/L3
// resident); blank edges rebuilt from NEG-padded LDS blkL. PW=16 register
// rings pinned with sched_barrier(0).
__global__ __launch_bounds__(256) void dp_k(
        const float* __restrict__ enc, const float* __restrict__ dec,
        const int* __restrict__ ilen, const int* __restrict__ tlen,
        const float* __restrict__ st, float* __restrict__ out) {
    int n = blockIdx.x;
    int tid = threadIdx.x;
    __shared__ float blkL[864];   // blkL[128+t] = enc[n][t][0]*L2E, NEG pads
    const float* encn = enc + (size_t)n * TT * VV;
    for (int i = tid; i < 864; i += 256)
        blkL[i] = (i >= 128 && i < 128 + TT) ? encn[(size_t)(i - 128) * VV] * L2E : NEG;
    __syncthreads();
    if (tid >= 64) return;
    int lane = tid;

    int tin = ilen[n], tg = tlen[n];
    int dend = tin - 1 + tg;
    const float* decn = dec + (size_t)n * UM * VV;
    float bd0 = decn[(size_t)min(2 * lane, UM - 1) * VV] * L2E;
    float bd1 = decn[(size_t)min(2 * lane + 1, UM - 1) * VV] * L2E;
    const float* sp = st + (size_t)n * DST * 128 + 2 * lane;
    int ib0 = 127 - 2 * lane;     // blkL idx of slot0's blk[t-1] is ib0 + d
    bool cap0 = (2 * lane == tg), cap1 = (2 * lane + 1 == tg);
    bool fx16 = (lane == 16), fx32 = (lane == 32), fx48 = (lane == 48);
    float a0 = (lane == 0) ? 0.0f : NEG;   // alpha[0][0] = 0 at d=0
    float a1 = NEG;
    float res = NEG;

    float Ae0[PW], Ae1[PW], Ab0[PW], Ab1[PW];
    float Be0[PW], Be1[PW], Bb0[PW], Bb1[PW];

    auto REFILL = [&](float (&Re0)[PW], float (&Re1)[PW],
                      float (&Rb0)[PW], float (&Rb1)[PW], int d0) {
#pragma unroll
        for (int k = 0; k < PW; ++k) {
            int d = d0 + k;
            float2 ev = *(const float2*)(sp + (size_t)d * 128);
            Re0[k] = ev.x; Re1[k] = ev.y;
            Rb0[k] = blkL[ib0 + d] + bd0;
            Rb1[k] = blkL[ib0 + d - 1] + bd1;
        }
        __builtin_amdgcn_sched_barrier(0);
    };

    auto STEPS = [&](float (&Re0)[PW], float (&Re1)[PW],
                     float (&Rb0)[PW], float (&Rb1)[PW], int d0) {
#pragma unroll
        for (int k = 0; k < PW; ++k) {
            int dd = d0 + k;
            // left neighbor of u=2L is lane L-1's a1: DPP row_shr:1 + seam fixups
            int sh = __builtin_amdgcn_update_dpp(__float_as_int(NEG), __float_as_int(a1),
                                                 0x111, 0xF, 0xF, false);   // row_shr:1
            float s15 = __int_as_float(__builtin_amdgcn_readlane(__float_as_int(a1), 15));
            float s31 = __int_as_float(__builtin_amdgcn_readlane(__float_as_int(a1), 31));
            float s47 = __int_as_float(__builtin_amdgcn_readlane(__float_as_int(a1), 47));
            float l0 = __int_as_float(sh);
            l0 = fx16 ? s15 : l0;
            l0 = fx32 ? s31 : l0;
            l0 = fx48 ? s47 : l0;
            float bt0 = a0 + Rb0[k], et0 = l0 + Re0[k];
            float bt1 = a1 + Rb1[k], et1 = a0 + Re1[k];   // old a0: same-lane left neighbor
            a0 = lae2(bt0, et0);
            a1 = lae2(bt1, et1);
            if (dd == dend) { if (cap0) res = a0; if (cap1) res = a1; }
        }
        __builtin_amdgcn_sched_barrier(0);
    };

    REFILL(Ae0, Ae1, Ab0, Ab1, 1);
    for (int d0 = 1; d0 <= dend; d0 += 2 * PW) {
        REFILL(Be0, Be1, Bb0, Bb1, d0 + PW);     STEPS(Ae0, Ae1, Ab0, Ab1, d0);
        REFILL(Ae0, Ae1, Ab0, Ab1, d0 + 2 * PW); STEPS(Be0, Be1, Bb0, Bb1, d0 + PW);
        // max d read = d0 + 3*PW - 1 <= dend + 47 <= 658 < DST; rows past 704 are
        // harness-poison (finite) and only consumed after res is captured.
    }

    if (cap0 | cap1) {
        float fin  = blkL[128 + tin - 1];
        float bdtg = decn[(size_t)tg * VV] * L2E;
        out[n] = (res + fin + bdtg) * LN2;
    }
}

extern "C" void kernel_launch(void* const* d_in, const int* in_sizes, int n_in,
                              void* d_out, int out_size, void* d_ws, size_t ws_size,
                              hipStream_t hs) {
    const float* enc  = (const float*)d_in[0];
    const float* dec  = (const float*)d_in[1];
    const int*   tgt  = (const int*)d_in[2];
    const int*   ilen = (const int*)d_in[3];
    const int*   tlen = (const int*)d_in[4];
    float* out = (float*)d_out;
    float* st  = (float*)d_ws;   // NB*DST*128 floats = 11.8 MB

    hipLaunchKernelGGL(build_k, dim3(NWIN, NB), dim3(256), 0, hs,
                       enc, dec, tgt, ilen, tlen, st);
    hipLaunchKernelGGL(dp_k, dim3(NB), dim3(256), 0, hs,
                       enc, dec, ilen, tlen, st, out);
}